// Round 5
// baseline (9771.702 us; speedup 1.0000x reference)
//
#include <hip/hip_runtime.h>

// Problem constants (B=8, C=32, H=192, W=320)
#define IMH 192
#define IMW 320
#define HW_ (IMH * IMW)      // 61440
#define BB 8
#define FC 32
#define SLOT 36              // NHWC accumulator slot: 32 feat + 1 norm + 3 pad (144B, 16B-aligned)

typedef unsigned short ushortT;
typedef __attribute__((ext_vector_type(8))) short short8;   // 8 bf16 = 4 VGPRs
typedef __attribute__((ext_vector_type(4))) float f32x4;

union FragU { uint4 u; short8 s8; };

__device__ __forceinline__ ushortT f2bf(float x) {
    union { float f; unsigned u; } v; v.f = x;
    unsigned r = v.u + 0x7FFF + ((v.u >> 16) & 1);   // RNE
    return (ushortT)(r >> 16);
}
__device__ __forceinline__ float lk(float v) { return (v >= 0.f) ? v : 0.1f * v; }

// ---------------------------------------------------------------------------
// 1. bilinear 2x upsample (half-pixel centers, edge clamp) * 2.0  [full batch]
// ---------------------------------------------------------------------------
__global__ __launch_bounds__(256) void upsample_k(const float* __restrict__ in,
                                                  float* __restrict__ out) {
    int gid = blockIdx.x * 256 + threadIdx.x;
    const int total = BB * 4 * IMH * IMW;
    if (gid >= total) return;
    int ox = gid % IMW;
    int t  = gid / IMW;
    int oy = t % IMH;
    int bc = t / IMH;
    const int Hin = IMH / 2, Win = IMW / 2;
    float sy = oy * 0.5f - 0.25f;
    float sx = ox * 0.5f - 0.25f;
    float fy = floorf(sy), fx = floorf(sx);
    float ty_ = sy - fy, tx_ = sx - fx;
    int y0 = (int)fy, x0 = (int)fx;
    int y1 = y0 + 1, x1 = x0 + 1;
    y0 = max(0, min(Hin - 1, y0)); y1 = max(0, min(Hin - 1, y1));
    x0 = max(0, min(Win - 1, x0)); x1 = max(0, min(Win - 1, x1));
    const float* p = in + (long)bc * Hin * Win;
    float v00 = p[y0 * Win + x0], v01 = p[y0 * Win + x1];
    float v10 = p[y1 * Win + x0], v11 = p[y1 * Win + x1];
    float v = (1.f - ty_) * ((1.f - tx_) * v00 + tx_ * v01) +
              ty_ * ((1.f - tx_) * v10 + tx_ * v11);
    out[gid] = 2.f * v;
}

// ---------------------------------------------------------------------------
// 2. zero-init (16B granules)
// ---------------------------------------------------------------------------
__global__ __launch_bounds__(256) void zero4_k(uint4* __restrict__ p, long n) {
    long gid = (long)blockIdx.x * 256 + threadIdx.x;
    long stride = (long)gridDim.x * 256;
    uint4 z = make_uint4(0, 0, 0, 0);
    for (long i = gid; i < n; i += stride) p[i] = z;
}

// ---------------------------------------------------------------------------
// 3. softsplat scatter-add into NHWC fp32 accumulator [b][p][SLOT]
// ---------------------------------------------------------------------------
__global__ __launch_bounds__(256) void splat_k(const float* __restrict__ feat,
                                               const float* __restrict__ biflow,
                                               int fbase,
                                               float* __restrict__ acc, int nb) {
    int gid = blockIdx.x * 256 + threadIdx.x;
    if (gid >= nb * HW_) return;
    int b = gid / HW_;
    int p = gid - b * HW_;
    int y = p / IMW, x = p - y * IMW;
    const float* fl = biflow + ((long)b * 4 + fbase) * HW_;
    float fx = x + fl[p];
    float fy = y + fl[HW_ + p];
    float x0f = floorf(fx), y0f = floorf(fy);
    float wx1 = fx - x0f, wy1 = fy - y0f;
    float wx0 = 1.f - wx1, wy0 = 1.f - wy1;
    int ix0 = (int)x0f, iy0 = (int)y0f;

    float f[FC];
#pragma unroll
    for (int c = 0; c < FC; ++c) f[c] = feat[((long)b * FC + c) * HW_ + p];

    float* accb = acc + (long)b * HW_ * SLOT;
    const int ixs[4] = {ix0, ix0 + 1, ix0, ix0 + 1};
    const int iys[4] = {iy0, iy0, iy0 + 1, iy0 + 1};
    const float ww[4] = {wx0 * wy0, wx1 * wy0, wx0 * wy1, wx1 * wy1};
#pragma unroll
    for (int k = 0; k < 4; ++k) {
        int ix = ixs[k], iy = iys[k];
        float w = ww[k];
        if (ix < 0 || ix >= IMW || iy < 0 || iy >= IMH || w == 0.f) continue;
        float* slot = accb + (long)(iy * IMW + ix) * SLOT;
#pragma unroll
        for (int c = 0; c < FC; ++c) atomicAdd(&slot[c], f[c] * w);
        atomicAdd(&slot[32], w);
    }
}

// ---------------------------------------------------------------------------
// 4. correlation (9x9, mean over 32 ch) + leaky -> concat ch64..144 bf16.
//    Normalization fused: warped = acc/norm; inv0/32 folded into f, inv1 per q.
// ---------------------------------------------------------------------------
__global__ __launch_bounds__(256) void corr_k(const float* __restrict__ acc0,
                                              const float* __restrict__ acc1,
                                              ushortT* __restrict__ concat, int nb) {
    int gid = blockIdx.x * 256 + threadIdx.x;
    if (gid >= nb * HW_) return;
    int b = gid / HW_;
    int p = gid - b * HW_;
    int y = p / IMW, x = p - y * IMW;
    const float* a0 = acc0 + ((long)b * HW_ + p) * SLOT;
    const float* a1b = acc1 + (long)b * HW_ * SLOT;
    float w0 = a0[32];
    float inv0 = ((w0 == 0.f) ? 1.f : (1.f / w0)) * (1.f / 32.f);
    f32x4 f[8];
#pragma unroll
    for (int c4 = 0; c4 < 8; ++c4) {
        f32x4 v = *(const f32x4*)(a0 + c4 * 4);
        f[c4] = v * inv0;
    }
    ushortT* vb = concat + ((long)b * HW_ + p) * 160 + 64;
    for (int dy = 0; dy < 9; ++dy) {
        int yy = y + dy - 4;
        for (int dx = 0; dx < 9; ++dx) {
            int xx = x + dx - 4;
            float s = 0.f;
            if ((unsigned)yy < IMH && (unsigned)xx < IMW) {
                const float* a1 = a1b + (long)(yy * IMW + xx) * SLOT;
                float acc = 0.f;
#pragma unroll
                for (int c4 = 0; c4 < 8; ++c4) {
                    f32x4 v = *(const f32x4*)(a1 + c4 * 4);
                    acc = fmaf(f[c4][0], v[0], acc);
                    acc = fmaf(f[c4][1], v[1], acc);
                    acc = fmaf(f[c4][2], v[2], acc);
                    acc = fmaf(f[c4][3], v[3], acc);
                }
                float w1 = a1[32];
                s = acc * ((w1 == 0.f) ? 1.f : (1.f / w1));
            }
            vb[dy * 9 + dx] = f2bf(lk(s));
        }
    }
}

// ---------------------------------------------------------------------------
// 5. fill concat ch0..63: warped (NHWC acc, fused norm) + temporal (NCHW fp32)
// ---------------------------------------------------------------------------
__global__ __launch_bounds__(256) void fill_k(const float* __restrict__ acc,
                                              const float* __restrict__ tf,
                                              ushortT* __restrict__ concat, int nb) {
    int gid = blockIdx.x * 256 + threadIdx.x;
    if (gid >= nb * HW_) return;
    int b = gid / HW_;
    int p = gid - b * HW_;
    const float* a = acc + ((long)b * HW_ + p) * SLOT;
    float w = a[32];
    float inv = (w == 0.f) ? 1.f : (1.f / w);
    ushortT pk[64];
#pragma unroll
    for (int c4 = 0; c4 < 8; ++c4) {
        f32x4 v = *(const f32x4*)(a + c4 * 4);
#pragma unroll
        for (int j = 0; j < 4; ++j) pk[c4 * 4 + j] = f2bf(v[j] * inv);
    }
    const float* tb = tf + (long)b * FC * HW_ + p;
#pragma unroll
    for (int c = 0; c < FC; ++c) pk[32 + c] = f2bf(tb[(long)c * HW_]);
    uint4* dst = (uint4*)(concat + ((long)b * HW_ + p) * 160);
#pragma unroll
    for (int q = 0; q < 8; ++q) dst[q] = ((uint4*)pk)[q];
}

// ---------------------------------------------------------------------------
// 6. weight transform: W[oc][cin][3][3] fp32 -> Wb[tap][ocp][cinp] bf16 (pad 0)
// ---------------------------------------------------------------------------
__global__ __launch_bounds__(256) void wconv_k(const float* __restrict__ W,
                                               ushortT* __restrict__ dst,
                                               int OC, int OCp, int CIN, int CINp) {
    int gid = blockIdx.x * 256 + threadIdx.x;
    int total = 9 * OCp * CINp;
    if (gid >= total) return;
    int cin = gid % CINp;
    int t = gid / CINp;
    int oc = t % OCp;
    int tap = t / OCp;
    float v = 0.f;
    if (oc < OC && cin < CIN) v = W[((long)oc * CIN + cin) * 9 + tap];
    dst[gid] = f2bf(v);
}

// ---------------------------------------------------------------------------
// 7. MFMA implicit-GEMM conv3x3 (SAME). Block = 256 thr = 4 waves.
//    Tile: 2 rows x 64 px. Wave wv: row = wv>>1, px-half = (wv&1)*32, with
//    2 N-subtiles of 16 px. K = cin chunked by 32; 9 taps accumulated.
//    Stages 4 rows x 66 px x 32ch into LDS (19 KB, stride 36 -> conflict-free).
//    A frag: oc=lane&15, k=quad*8+j. B frag: px=lane&15, k=quad*8+j.
//    D: px=lane&15, oc=quad*4+reg.
// ---------------------------------------------------------------------------
template <int MT, int KC, bool LK, bool FIN>
__global__ __launch_bounds__(256) void mconv_k(
    const ushortT* __restrict__ act, int actStride, int cinReal,
    const ushortT* __restrict__ Wb,
    ushortT* __restrict__ outp, int outStride,
    const float* __restrict__ bfp, float* __restrict__ fout, int chBase) {

    const int CINp = KC * 32;
    const int OCp = MT * 16;
    const int tid = threadIdx.x;
    const int lane = tid & 63;
    const int wv = tid >> 6;
    const int l15 = lane & 15;
    const int quad = lane >> 4;
    const int r = wv >> 1;             // output row within band (0..1)
    const int stx = (wv & 1) * 32;     // px-half base
    const int x0 = blockIdx.x * 64;    // 5 col tiles
    const int y0 = blockIdx.y * 2;     // 96 row bands
    const int b = blockIdx.z;          // local batch

    __shared__ ushortT sAct[4 * 66 * 36];   // 19,008 B

    f32x4 acc[2][MT];
#pragma unroll
    for (int s = 0; s < 2; ++s)
#pragma unroll
        for (int i = 0; i < MT; ++i) acc[s][i] = (f32x4)0.f;

    const long pixBase = (long)b * HW_;

    for (int kc = 0; kc < KC; ++kc) {
        __syncthreads();
        // stage 4 rows x 66 px x 32 ch (4 units of 8ch per site)
        for (int u = tid; u < 4 * 66 * 4; u += 256) {
            int c8 = u & 3;
            int site = u >> 2;
            int ky = site / 66;
            int xi = site - ky * 66;
            int gy = y0 + ky - 1;
            int gx = x0 + xi - 1;
            int cBeg = kc * 32 + c8 * 8;
            ushortT* dp = &sAct[site * 36 + c8 * 8];
            if ((unsigned)gy < IMH && (unsigned)gx < IMW && cBeg < cinReal) {
                const ushortT* sp = act + ((pixBase + (long)gy * IMW + gx) * actStride + cBeg);
                if (cBeg + 8 <= cinReal) {
                    const uint2* sq = (const uint2*)sp;
                    ((uint2*)dp)[0] = sq[0];
                    ((uint2*)dp)[1] = sq[1];
                } else {
#pragma unroll
                    for (int j = 0; j < 8; ++j)
                        dp[j] = (cBeg + j < cinReal) ? sp[j] : (ushortT)0;
                }
            } else {
                uint2 z = make_uint2(0, 0);
                ((uint2*)dp)[0] = z;
                ((uint2*)dp)[1] = z;
            }
        }
        __syncthreads();

#pragma unroll
        for (int tap = 0; tap < 9; ++tap) {
            const int ky = tap / 3, kx = tap % 3;
            FragU bf[2];
#pragma unroll
            for (int st = 0; st < 2; ++st) {
                const int xi = stx + st * 16 + l15 + kx;
                const uint2* bp = (const uint2*)&sAct[(((r + ky) * 66) + xi) * 36 + quad * 8];
                uint2 b0 = bp[0], b1 = bp[1];
                bf[st].u = make_uint4(b0.x, b0.y, b1.x, b1.y);
            }
            const ushortT* wp = Wb + (((long)tap * OCp + l15) * CINp + kc * 32 + quad * 8);
#pragma unroll
            for (int mt = 0; mt < MT; ++mt) {
                FragU af;
                af.u = *(const uint4*)(wp + (long)mt * 16 * CINp);
                acc[0][mt] = __builtin_amdgcn_mfma_f32_16x16x32_bf16(af.s8, bf[0].s8, acc[0][mt], 0, 0, 0);
                acc[1][mt] = __builtin_amdgcn_mfma_f32_16x16x32_bf16(af.s8, bf[1].s8, acc[1][mt], 0, 0, 0);
            }
        }
    }

    const int y = y0 + r;
    if (FIN) {
        if (quad == 0) {
#pragma unroll
            for (int st = 0; st < 2; ++st) {
                const int px = x0 + stx + st * 16 + l15;
#pragma unroll
                for (int rg = 0; rg < 2; ++rg) {
                    float v = lk(acc[st][0][rg]);
                    long o = ((long)(b * 4 + chBase + rg) * IMH + y) * IMW + px;
                    fout[o] = bfp[o] + v;
                }
            }
        }
    } else {
#pragma unroll
        for (int st = 0; st < 2; ++st) {
            const int px = x0 + stx + st * 16 + l15;
            long obase = (pixBase + (long)y * IMW + px) * outStride;
#pragma unroll
            for (int mt = 0; mt < MT; ++mt) {
                int oc = mt * 16 + quad * 4;
                ushortT pk[4];
#pragma unroll
                for (int rg = 0; rg < 4; ++rg) {
                    float v = acc[st][mt][rg];
                    if (LK) v = lk(v);
                    pk[rg] = f2bf(v);
                }
                *(uint2*)&outp[obase + oc] = *(uint2*)pk;
            }
        }
    }
}

// ---------------------------------------------------------------------------
// launch — ws-size-adaptive batch grouping (round-4 evidence: ws >= ~421 MB)
// ---------------------------------------------------------------------------
extern "C" void kernel_launch(void* const* d_in, const int* in_sizes, int n_in,
                              void* d_out, int out_size, void* d_ws, size_t ws_size,
                              hipStream_t stream) {
    const float* f0  = (const float*)d_in[0];
    const float* f1  = (const float*)d_in[1];
    const float* bfp = (const float*)d_in[2];
    const float* ftf = (const float*)d_in[3];
    const float* btf = (const float*)d_in[4];
    const float* W1  = (const float*)d_in[5];
    const float* W2  = (const float*)d_in[6];
    const float* W3  = (const float*)d_in[7];
    const float* W4  = (const float*)d_in[8];
    const float* W5  = (const float*)d_in[9];
    const float* W6  = (const float*)d_in[10];
    const float* W7  = (const float*)d_in[11];
    float* out = (float*)d_out;

    // fixed: biflow + transposed weights; per-batch: acc0+acc1 (SLOT fp32) +
    // concat (160 bf16) + bufA/B (64 bf16) = (288+320+256) = 864 B/px
    char* base = (char*)d_ws;
    size_t off = 0;
    auto alloc = [&](size_t bytes) { char* p = base + off; off += (bytes + 255) & ~(size_t)255; return p; };

    float* biflow = (float*)alloc((size_t)BB * 4 * HW_ * 4);
    ushortT* WbL1 = (ushortT*)alloc((size_t)9 * 64 * 160 * 2);
    ushortT* WbL2 = (ushortT*)alloc((size_t)9 * 64 * 64 * 2);
    ushortT* WbL3 = (ushortT*)alloc((size_t)9 * 64 * 64 * 2);
    ushortT* WbL4 = (ushortT*)alloc((size_t)9 * 32 * 64 * 2);
    ushortT* WbL5 = (ushortT*)alloc((size_t)9 * 32 * 32 * 2);
    ushortT* WbL6 = (ushortT*)alloc((size_t)9 * 16 * 32 * 2);
    ushortT* WbL7 = (ushortT*)alloc((size_t)9 * 16 * 32 * 2);

    const size_t PERB = (size_t)864 * HW_;
    size_t remain = (ws_size > off + 4096) ? (ws_size - off - 4096) : 0;
    int NB = (int)(remain / (PERB + 4096));
    if (NB < 1) NB = 1;
    if (NB > BB) NB = BB;

    float*   acc0   = (float*)alloc((size_t)NB * HW_ * SLOT * 4);
    float*   acc1   = (float*)alloc((size_t)NB * HW_ * SLOT * 4);
    ushortT* concat = (ushortT*)alloc((size_t)NB * HW_ * 160 * 2);
    ushortT* bufA   = (ushortT*)alloc((size_t)NB * HW_ * 64 * 2);
    ushortT* bufB   = (ushortT*)alloc((size_t)NB * HW_ * 64 * 2);

    upsample_k<<<(BB * 4 * HW_ + 255) / 256, 256, 0, stream>>>(bfp, biflow);

    wconv_k<<<(9 * 64 * 160 + 255) / 256, 256, 0, stream>>>(W1, WbL1, 64, 64, 145, 160);
    wconv_k<<<(9 * 64 * 64 + 255) / 256, 256, 0, stream>>>(W2, WbL2, 64, 64, 64, 64);
    wconv_k<<<(9 * 64 * 64 + 255) / 256, 256, 0, stream>>>(W3, WbL3, 64, 64, 64, 64);
    wconv_k<<<(9 * 32 * 64 + 255) / 256, 256, 0, stream>>>(W4, WbL4, 32, 32, 64, 64);
    wconv_k<<<(9 * 32 * 32 + 255) / 256, 256, 0, stream>>>(W5, WbL5, 32, 32, 32, 32);
    wconv_k<<<(9 * 16 * 32 + 255) / 256, 256, 0, stream>>>(W6, WbL6, 16, 16, 32, 32);
    wconv_k<<<(9 * 16 * 32 + 255) / 256, 256, 0, stream>>>(W7, WbL7, 2, 16, 16, 32);

    for (int g = 0; g < BB; g += NB) {
        const int nb = (BB - g < NB) ? (BB - g) : NB;
        const int npix = nb * HW_;
        const float* f0g  = f0 + (size_t)g * FC * HW_;
        const float* f1g  = f1 + (size_t)g * FC * HW_;
        const float* ftfg = ftf + (size_t)g * FC * HW_;
        const float* btfg = btf + (size_t)g * FC * HW_;
        const float* bflg = biflow + (size_t)g * 4 * HW_;
        float* outg = out + (size_t)g * 4 * HW_;

        // acc0 and acc1 are contiguous (alloc sizes are 256B-multiples)
        zero4_k<<<2048, 256, 0, stream>>>((uint4*)acc0, (long)2 * nb * HW_ * SLOT / 4);
        splat_k<<<(npix + 255) / 256, 256, 0, stream>>>(f0g, bflg, 0, acc0, nb);
        splat_k<<<(npix + 255) / 256, 256, 0, stream>>>(f1g, bflg, 2, acc1, nb);
        corr_k<<<(npix + 255) / 256, 256, 0, stream>>>(acc0, acc1, concat, nb);

        dim3 cg(5, 96, nb);
        for (int pass = 0; pass < 2; ++pass) {
            const float* ac = pass ? acc1 : acc0;
            const float* tf = pass ? btfg : ftfg;
            int chB = pass ? 2 : 0;
            fill_k<<<(npix + 255) / 256, 256, 0, stream>>>(ac, tf, concat, nb);
            mconv_k<4, 5, false, false><<<cg, 256, 0, stream>>>(concat, 160, 160, WbL1, bufA, 64, nullptr, nullptr, 0);
            mconv_k<4, 2, false, false><<<cg, 256, 0, stream>>>(bufA, 64, 64, WbL2, bufB, 64, nullptr, nullptr, 0);
            mconv_k<4, 2, true,  false><<<cg, 256, 0, stream>>>(bufB, 64, 64, WbL3, bufA, 64, nullptr, nullptr, 0);
            mconv_k<2, 2, false, false><<<cg, 256, 0, stream>>>(bufA, 64, 64, WbL4, bufB, 32, nullptr, nullptr, 0);
            mconv_k<2, 1, false, false><<<cg, 256, 0, stream>>>(bufB, 32, 32, WbL5, bufA, 32, nullptr, nullptr, 0);
            mconv_k<1, 1, false, false><<<cg, 256, 0, stream>>>(bufA, 32, 32, WbL6, bufB, 16, nullptr, nullptr, 0);
            mconv_k<1, 1, true,  true ><<<cg, 256, 0, stream>>>(bufB, 16, 16, WbL7, nullptr, 0, bflg, outg, chB);
        }
    }
}